// Round 2
// baseline (161.988 us; speedup 1.0000x reference)
//
#include <hip/hip_runtime.h>
#include <hip/hip_bf16.h>
#include <math.h>

// VariableSelectionNetwork — MI355X (gfx950)
//
// Key identity: the reference applies LayerNorm over a size-1 axis inside the
// scorer => that LN's output is exactly sc_ln_b (its bias), independent of
// data. So softmax weights W[f] = softmax(sc_ln_b) are constant, and the
// whole scorer GRN (sc_fc1/fc2/gate/skip, ~90% of reference FLOPs) is dead
// code. Remaining per token: mix = (W*x) @ proj_w + c ; post-GRN (3x 256x256
// matvecs via bf16 MFMA, fp32 accumulate) ; gated skip ; LayerNorm(256).
//
// All inputs/outputs are fp32 (reference dtypes). bf16 is used only for MFMA
// operands; skip paths and epilogues stay fp32 (2%-relative threshold).

typedef __bf16 bf16;
typedef __bf16 bf16x8 __attribute__((ext_vector_type(8)));
typedef float f32x4 __attribute__((ext_vector_type(4)));

#define NTOK 8192   // B*T
#define MT   16     // tokens per block (one MFMA M-tile)
#define D_   256
#define F_   32

__global__ __launch_bounds__(64) void vsn_kernel(
    const float* __restrict__ x,        // [NTOK, F]
    const float* __restrict__ proj_w,   // [F, D]
    const float* __restrict__ proj_b,   // [F, D]
    const float* __restrict__ sc_ln_b,  // [F]
    const float* __restrict__ fc1_w,    // [H, D]
    const float* __restrict__ fc1_b,    // [H]
    const float* __restrict__ fc2_w,    // [D, H]
    const float* __restrict__ fc2_b,    // [D]
    const float* __restrict__ gate_w,   // [D, D]
    const float* __restrict__ gate_b,   // [D]
    const float* __restrict__ ln_g,     // [D]
    const float* __restrict__ ln_b,     // [D]
    float* __restrict__ out)            // [NTOK, D]
{
  __shared__ float sW[F_];          // softmax(sc_ln_b)
  __shared__ float sC[D_];          // c[d] = sum_f W[f]*proj_b[f][d]
  __shared__ bf16  sXW[MT][40];     // xw[t][f] = W[f]*x[t][f]  (rows 80B, 16B-aligned)
  __shared__ float sMixF[MT][260];  // mix, fp32 (skip path); 260*4=1040B rows (16B-aligned)
  __shared__ bf16  sMixB[MT][264];  // mix, bf16 (MFMA A operand); 264*2=528B rows
  __shared__ bf16  sH1[MT][264];    // elu(fc1) bf16
  __shared__ float sH2F[MT][260];   // fc2 out fp32 (then reused for y2)
  __shared__ bf16  sH2B[MT][264];   // fc2 out bf16

  const int lane = threadIdx.x;
  const int tok0 = blockIdx.x * MT;
  const int lm = lane & 15;   // MFMA: A-row m / B-col n / C-col n
  const int lq = lane >> 4;   // quad 0..3

  // ---------- phase 0a: W = softmax(sc_ln_b) ----------
  float logit = (lane < F_) ? sc_ln_b[lane] : -3.0e38f;
  float mx = logit;
  #pragma unroll
  for (int off = 32; off; off >>= 1) mx = fmaxf(mx, __shfl_xor(mx, off));
  float e = (lane < F_) ? __expf(logit - mx) : 0.0f;
  float se = e;
  #pragma unroll
  for (int off = 32; off; off >>= 1) se += __shfl_xor(se, off);
  if (lane < F_) sW[lane] = e / se;
  __syncthreads();

  // ---------- phase 0b: c[d] = sum_f W[f] * proj_b[f][d] ----------
  #pragma unroll
  for (int i = 0; i < 4; i++) {
    int d = lane + 64 * i;
    float acc = 0.0f;
    #pragma unroll
    for (int f = 0; f < F_; f++)
      acc += sW[f] * proj_b[f * D_ + d];
    sC[d] = acc;
  }

  // ---------- phase 0c: xw[t][f] = W[f]*x[t][f], cast bf16 ----------
  {
    int t  = lane >> 2;
    int f0 = (lane & 3) * 8;
    const float* xp = x + (size_t)(tok0 + t) * F_ + f0;
    #pragma unroll
    for (int j = 0; j < 8; j++)
      sXW[t][f0 + j] = (bf16)(sW[f0 + j] * xp[j]);
  }
  __syncthreads();

  // ---------- phase 1: mix = xw @ proj_w + c   (K = F = 32, one MFMA step) ----------
  {
    bf16x8 a0 = *(const bf16x8*)(&sXW[lm][lq * 8]);
    f32x4 accm[16];
    #pragma unroll
    for (int j = 0; j < 16; j++) {
      float cv = sC[j * 16 + lm];
      f32x4 acc = {cv, cv, cv, cv};
      bf16x8 b;
      #pragma unroll
      for (int jj = 0; jj < 8; jj++)   // B[k][n] = proj_w[k*D + n]
        b[jj] = (bf16)proj_w[(lq * 8 + jj) * D_ + j * 16 + lm];
      accm[j] = __builtin_amdgcn_mfma_f32_16x16x32_bf16(a0, b, acc, 0, 0, 0);
    }
    #pragma unroll
    for (int j = 0; j < 16; j++) {
      int n = j * 16 + lm;
      #pragma unroll
      for (int r = 0; r < 4; r++) {
        int m = lq * 4 + r;          // C/D: row = quad*4 + reg, col = lane&15
        float v = accm[j][r];
        sMixF[m][n] = v;
        sMixB[m][n] = (bf16)v;
      }
    }
  }
  __syncthreads();

  // generic [16,256] @ W[256,256]^T MFMA layer (A bf16 in LDS, B rows fp32 from global)
  auto gemm256 = [&](const bf16 (*A)[264], const float* __restrict__ W, f32x4* acc) {
    bf16x8 af[8];
    #pragma unroll
    for (int ks = 0; ks < 8; ks++)
      af[ks] = *(const bf16x8*)(&A[lm][ks * 32 + lq * 8]);
    #pragma unroll
    for (int j = 0; j < 16; j++) {
      f32x4 z = {0.f, 0.f, 0.f, 0.f};
      acc[j] = z;
      const float* wrow = W + (size_t)(j * 16 + lm) * 256 + lq * 8;
      #pragma unroll
      for (int ks = 0; ks < 8; ks++) {
        bf16x8 b;
        #pragma unroll
        for (int jj = 0; jj < 8; jj++)
          b[jj] = (bf16)wrow[ks * 32 + jj];
        acc[j] = __builtin_amdgcn_mfma_f32_16x16x32_bf16(af[ks], b, acc[j], 0, 0, 0);
      }
    }
  };

  // ---------- phase 2: h1 = elu(mix @ fc1^T + b1) ----------
  {
    f32x4 acc[16];
    gemm256(sMixB, fc1_w, acc);
    #pragma unroll
    for (int j = 0; j < 16; j++) {
      int n = j * 16 + lm;
      float bias = fc1_b[n];
      #pragma unroll
      for (int r = 0; r < 4; r++) {
        int m = lq * 4 + r;
        float v = acc[j][r] + bias;
        v = (v > 0.0f) ? v : (__expf(v) - 1.0f);
        sH1[m][n] = (bf16)v;
      }
    }
  }
  __syncthreads();

  // ---------- phase 3: h2 = h1 @ fc2^T + b2 ----------
  {
    f32x4 acc[16];
    gemm256(sH1, fc2_w, acc);
    #pragma unroll
    for (int j = 0; j < 16; j++) {
      int n = j * 16 + lm;
      float bias = fc2_b[n];
      #pragma unroll
      for (int r = 0; r < 4; r++) {
        int m = lq * 4 + r;
        float v = acc[j][r] + bias;
        sH2F[m][n] = v;
        sH2B[m][n] = (bf16)v;
      }
    }
  }
  __syncthreads();

  // ---------- phase 4: g = sigmoid(h2 @ gate^T + gb); y2 = g*h2 + (1-g)*mix ----------
  {
    f32x4 acc[16];
    gemm256(sH2B, gate_w, acc);
    #pragma unroll
    for (int j = 0; j < 16; j++) {
      int n = j * 16 + lm;
      float bias = gate_b[n];
      #pragma unroll
      for (int r = 0; r < 4; r++) {
        int m = lq * 4 + r;
        float s = acc[j][r] + bias;
        float g = 1.0f / (1.0f + __expf(-s));
        float y = g * sH2F[m][n] + (1.0f - g) * sMixF[m][n];
        sH2F[m][n] = y;   // each (m,n) owned by exactly one lane/reg -> safe
      }
    }
  }
  __syncthreads();

  // ---------- phase 5: LayerNorm over D, write fp32 out (float4 coalesced) ----------
  float4 gv = *(const float4*)(ln_g + lane * 4);
  float4 bv = *(const float4*)(ln_b + lane * 4);
  const float inv_d = 1.0f / 256.0f;
  for (int t = 0; t < MT; t++) {
    float4 yv = *(const float4*)(&sH2F[t][lane * 4]);
    float s = yv.x + yv.y + yv.z + yv.w;
    #pragma unroll
    for (int off = 32; off; off >>= 1) s += __shfl_xor(s, off);
    float mean = s * inv_d;
    float q;
    {
      float d0 = yv.x - mean, d1 = yv.y - mean, d2 = yv.z - mean, d3 = yv.w - mean;
      q = d0 * d0 + d1 * d1 + d2 * d2 + d3 * d3;
    }
    #pragma unroll
    for (int off = 32; off; off >>= 1) q += __shfl_xor(q, off);
    float rstd = rsqrtf(q * inv_d + 1e-5f);
    float4 o;
    o.x = (yv.x - mean) * rstd * gv.x + bv.x;
    o.y = (yv.y - mean) * rstd * gv.y + bv.y;
    o.z = (yv.z - mean) * rstd * gv.z + bv.z;
    o.w = (yv.w - mean) * rstd * gv.w + bv.w;
    *(float4*)(out + (size_t)(tok0 + t) * D_ + lane * 4) = o;
  }
}

extern "C" void kernel_launch(void* const* d_in, const int* in_sizes, int n_in,
                              void* d_out, int out_size, void* d_ws, size_t ws_size,
                              hipStream_t stream) {
  (void)in_sizes; (void)n_in; (void)d_ws; (void)ws_size; (void)out_size;
  const float* x      = (const float*)d_in[0];
  const float* proj_w = (const float*)d_in[1];
  const float* proj_b = (const float*)d_in[2];
  const float* sclnb  = (const float*)d_in[12];
  const float* fc1w   = (const float*)d_in[13];
  const float* fc1b   = (const float*)d_in[14];
  const float* fc2w   = (const float*)d_in[15];
  const float* fc2b   = (const float*)d_in[16];
  const float* gw     = (const float*)d_in[17];
  const float* gb     = (const float*)d_in[18];
  const float* lng    = (const float*)d_in[19];
  const float* lnb    = (const float*)d_in[20];
  vsn_kernel<<<NTOK / MT, 64, 0, stream>>>(x, proj_w, proj_b, sclnb,
                                           fc1w, fc1b, fc2w, fc2b,
                                           gw, gb, lng, lnb, (float*)d_out);
}